// Round 4
// baseline (349.300 us; speedup 1.0000x reference)
//
#include <hip/hip_runtime.h>
#include <math.h>

#define N_BOX 8192
#define NW 128              // 8192 / 64 words per row
#define CAP 48              // staged candidate rows per group (fallback past this)
#define THR_C 0.7f
#define IOU_THR_C 0.5f
#define EPS_C 1e-9f

// SCALER = max(3508/1280, 2480/1280) computed in double then rounded to f32,
// matching numpy/jax float32 weak-typed scalar promotion.
__device__ __constant__ float kScaler = (float)(3508.0 / 1280.0);

// async global->LDS DMA, 16 B/lane: lane l's 16 B land at ldsbase + l*16.
static __device__ __forceinline__ void gload_lds16(const void* gp, void* lp) {
    __builtin_amdgcn_global_load_lds(
        (const __attribute__((address_space(1))) unsigned int*)gp,
        (__attribute__((address_space(3))) unsigned int*)lp,
        16, 0, 0);
}

static __device__ __forceinline__ unsigned long long make_key(const float* conf, int i) {
    float c0 = conf[2 * i], c1 = conf[2 * i + 1];
    bool valid = (c0 > THR_C) || (c1 > THR_C);
    float ms = valid ? fmaxf(c0, c1) : -INFINITY;
    unsigned int u = __float_as_uint(ms);
    unsigned int m = (u & 0x80000000u) ? ~u : (u | 0x80000000u); // ascending map
    unsigned int d = ~m;                                          // descending key
    return ((unsigned long long)d << 32) | (unsigned int)i;
}

// ---------------------------------------------------------------------------
// Sort: full 8192 bitonic network split so passes with j<=1024 run LDS-locally
// in 4 blocks of 2048 elements; only (k=4096,j=2048), (k=8192,j=4096),
// (k=8192,j=2048) are global passes. Directions use GLOBAL indices, so the
// network is bit-identical to the verified single-block version.
// ---------------------------------------------------------------------------
__global__ __launch_bounds__(1024) void sort_local1(const float* __restrict__ conf,
                                                    unsigned long long* __restrict__ keys) {
    __shared__ unsigned long long s[2048];
    int base = blockIdx.x * 2048;
    for (int l = threadIdx.x; l < 2048; l += 1024) s[l] = make_key(conf, base + l);
    __syncthreads();
    for (int k = 2; k <= 2048; k <<= 1) {
        for (int j = k >> 1; j > 0; j >>= 1) {
            int t = threadIdx.x;
            int i = ((t & ~(j - 1)) << 1) | (t & (j - 1));
            int p = i | j;
            bool up = (((base + i) & k) == 0);
            unsigned long long a = s[i], b = s[p];
            bool sw = up ? (a > b) : (a < b);
            if (sw) { s[i] = b; s[p] = a; }
            __syncthreads();
        }
    }
    for (int l = threadIdx.x; l < 2048; l += 1024) keys[base + l] = s[l];
}

__global__ void sort_global(unsigned long long* __restrict__ keys, int k, int j) {
    int t = blockIdx.x * 256 + threadIdx.x;          // 4096 threads
    int i = ((t & ~(j - 1)) << 1) | (t & (j - 1));
    int p = i | j;
    bool up = ((i & k) == 0);
    unsigned long long a = keys[i], b = keys[p];
    bool sw = up ? (a > b) : (a < b);
    if (sw) { keys[i] = b; keys[p] = a; }
}

// Local passes j=1024..1 for merge step k. When doGather!=0 (final k=8192 run)
// the sorted chunk is consumed directly from LDS: writes sb/order/validw and
// zero-inits nzoffG (block 0) instead of storing keys.
__global__ __launch_bounds__(1024) void sort_local2(unsigned long long* __restrict__ keys,
                                                    int k, int doGather,
                                                    const float* __restrict__ bboxes,
                                                    const float* __restrict__ conf,
                                                    float4* __restrict__ sb,
                                                    unsigned int* __restrict__ order,
                                                    unsigned long long* __restrict__ validw,
                                                    unsigned long long* __restrict__ nzoffG) {
    __shared__ unsigned long long s[2048];
    int base = blockIdx.x * 2048;
    for (int l = threadIdx.x; l < 2048; l += 1024) s[l] = keys[base + l];
    __syncthreads();
    for (int j = 1024; j > 0; j >>= 1) {
        int t = threadIdx.x;
        int i = ((t & ~(j - 1)) << 1) | (t & (j - 1));
        int p = i | j;
        bool up = (((base + i) & k) == 0);
        unsigned long long a = s[i], b = s[p];
        bool sw = up ? (a > b) : (a < b);
        if (sw) { s[i] = b; s[p] = a; }
        __syncthreads();
    }
    if (!doGather) {
        for (int l = threadIdx.x; l < 2048; l += 1024) keys[base + l] = s[l];
    } else {
        if (blockIdx.x == 0 && threadIdx.x < NW) nzoffG[threadIdx.x] = 0ull;
        for (int l = threadIdx.x; l < 2048; l += 1024) {
            int gi = base + l;
            unsigned int o = (unsigned int)(s[l] & 0xffffffffull);
            order[gi] = o;
            sb[gi] = ((const float4*)bboxes)[o];
            float c0 = conf[2 * o], c1 = conf[2 * o + 1];
            unsigned long long vb = __ballot((c0 > THR_C) || (c1 > THR_C));
            if ((l & 63) == 0) validw[gi >> 6] = vb;
        }
    }
}

// ---------------------------------------------------------------------------
// Kernel 3: suppression bit-matrix + sparsity metadata.
//   mask[i][w] bit b = (iou(i, 64w+b) > thr && 64w+b > i)
//   diagG[i]  = mask[i][i>>6]; dnzG[w] bit r = diag word nonzero;
//   nzoffG[w] bit r = row 64w+r has a nonzero off-diagonal word.
// Dead-work skip: invalid rows (never read downstream: nzoff/dnz exclude
// them, suppressing removed rows is idempotent) and lower-triangle words
// compute nothing; invalid rows also skip the mask store.
// ---------------------------------------------------------------------------
__global__ void mask_kernel(const float4* __restrict__ sb,
                            const unsigned long long* __restrict__ validw,
                            unsigned long long* __restrict__ mask,
                            unsigned long long* __restrict__ diagG,
                            unsigned long long* __restrict__ dnzG,
                            unsigned long long* __restrict__ nzoffG) {
    __shared__ float4 cb[64];
    __shared__ float carea[64];
    int w = blockIdx.y;
    if (threadIdx.x < 64) {
        float4 c = sb[(w << 6) + threadIdx.x];
        cb[threadIdx.x] = c;
        carea[threadIdx.x] = (c.z - c.x) * (c.w - c.y);
    }
    __syncthreads();
    int i = blockIdx.x * 256 + threadIdx.x;
    bool iv = (validw[i >> 6] >> (i & 63)) & 1ull;
    int jbase = w << 6;
    unsigned long long bits = 0ull;
    if (iv && (jbase + 63 > i)) {
        float4 r = sb[i];
        float ra = (r.z - r.x) * (r.w - r.y);
#pragma unroll 8
        for (int b = 0; b < 64; ++b) {
            float4 c = cb[b];
            float iw = fminf(r.z, c.z) - fmaxf(r.x, c.x);
            float ih = fminf(r.w, c.w) - fmaxf(r.y, c.y);
            iw = fmaxf(iw, 0.0f);
            ih = fmaxf(ih, 0.0f);
            float inter = iw * ih;
            float iou = inter / (ra + carea[b] - inter + EPS_C);
            if ((iou > IOU_THR_C) && ((jbase + b) > i)) bits |= (1ull << b);
        }
    }
    unsigned long long bb = __ballot(bits != 0ull);
    if ((i >> 6) == w) {
        diagG[i] = bits;
        if ((i & 63) == 0) dnzG[w] = bb;
    } else {
        if (bb && ((i & 63) == 0)) atomicOr(&nzoffG[i >> 6], bb);
    }
    if (iv) mask[(size_t)i * NW + w] = bits;
}

// ---------------------------------------------------------------------------
// Kernel 4: block-parallel greedy scan with one-group-ahead LDS prefetch.
// Candidate set for group g = nzoff[g] & ~rem[g] snapshotted in the stable
// B1-B2 window (monotone over-approx of final kept rows; filtered by kwS at
// apply time). Rows staged via global_load_lds into double-buffered cbuf, so
// apply reads LDS and the global latency hides under the previous group's
// apply phase. keep words collected in LDS, one global store at the end.
// ---------------------------------------------------------------------------
__global__ __launch_bounds__(256) void scan_kernel(const unsigned long long* __restrict__ mask,
                                                   const unsigned long long* __restrict__ validw,
                                                   const unsigned long long* __restrict__ diagG,
                                                   const unsigned long long* __restrict__ dnzG,
                                                   const unsigned long long* __restrict__ nzoffG,
                                                   unsigned long long* __restrict__ keepw) {
    __shared__ unsigned long long cbuf[2][CAP][NW];   // 96 KiB staged rows
    __shared__ unsigned long long dbuf[2][NW];        // staged diag words (64 used)
    __shared__ unsigned long long remL[NW];
    __shared__ unsigned long long dnzL[NW];
    __shared__ unsigned long long nzoffL[NW];
    __shared__ unsigned long long keepL[NW];
    __shared__ unsigned long long kwS;
    int t = threadIdx.x;
    int lane = t & 63;
    int wv = t >> 6;                       // wave 0..3
    int wd = t & 127;
    int par = t >> 7;
    for (int w = t; w < NW; w += 256) {
        remL[w] = ~validw[w];
        dnzL[w] = dnzG[w];
        nzoffL[w] = nzoffG[w];
    }
    __syncthreads();
    // prefetch group 0 (remL stable here; all waves enumerate identically)
    unsigned long long cwCur = nzoffL[0] & ~remL[0];
    {
        unsigned long long tmp = cwCur;
        int j = 0;
        while (tmp && j < CAP) {
            int r = __builtin_ctzll(tmp); tmp &= tmp - 1;
            if ((j & 3) == wv)
                gload_lds16((const char*)(mask + (size_t)r * NW) + lane * 16, &cbuf[0][j][0]);
            ++j;
        }
        if (wv == 0) gload_lds16((const char*)diagG + lane * 16, &dbuf[0][0]);
    }
    for (int g = 0; g < NW; ++g) {
        int b = g & 1;
        __syncthreads();   // B1: prefetch(g) landed (vmcnt drain), remL stable
        // stable window: snapshot next group's candidates (uniform across waves)
        unsigned long long cwNext = (g + 1 < NW) ? (nzoffL[g + 1] & ~remL[g + 1]) : 0ull;
        if (t < 64) {
            unsigned long long cur = remL[g];
            unsigned long long dn = dnzL[g];
            while (dn) {
                int r = __builtin_ctzll(dn); dn &= dn - 1;
                if (!((cur >> r) & 1ull)) cur |= dbuf[b][r];
            }
            if (t == 0) { keepL[g] = cur; kwS = ~cur; }
        }
        __syncthreads();   // B2: kwS ready
        unsigned long long kw = kwS;
        // issue prefetch(g+1): fire-and-forget, drains at next B1
        if (g + 1 < NW) {
            int b1 = 1 - b;
            unsigned long long tmp = cwNext;
            int j = 0;
            while (tmp && j < CAP) {
                int r = __builtin_ctzll(tmp); tmp &= tmp - 1;
                if ((j & 3) == wv)
                    gload_lds16((const char*)(mask + (size_t)(((g + 1) << 6) + r) * NW) + lane * 16,
                                &cbuf[b1][j][0]);
                ++j;
            }
            if (wv == 0)
                gload_lds16((const char*)(diagG + ((g + 1) << 6)) + lane * 16, &dbuf[b1][0]);
        }
        // apply(g): OR kept candidate rows into later removal words
        if (wd > g && (kw & cwCur)) {
            unsigned long long tmp = cwCur;
            unsigned long long acc = 0ull;
            int j = 0;
            while (tmp) {
                int r = __builtin_ctzll(tmp); tmp &= tmp - 1;
                if ((j & 1) == par && ((kw >> r) & 1ull)) {
                    acc |= (j < CAP) ? cbuf[b][j][wd]
                                     : mask[(size_t)((g << 6) + r) * NW + wd];
                }
                ++j;
            }
            if (acc) atomicOr(&remL[wd], acc);
        }
        cwCur = cwNext;
    }
    __syncthreads();
    for (int w = t; w < NW; w += 256) keepw[w] = keepL[w];
}

// ---------------------------------------------------------------------------
// Kernel 5: write (N,6) output: [boxes*SCALER*kf, conf*kf]
// ---------------------------------------------------------------------------
__global__ void out_kernel(const float4* __restrict__ sb,
                           const unsigned long long* __restrict__ keepw,
                           const unsigned int* __restrict__ order,
                           const float* __restrict__ conf,
                           float* __restrict__ out) {
    int i = blockIdx.x * 256 + threadIdx.x;
    float kf = ((keepw[i >> 6] >> (i & 63)) & 1ull) ? 0.0f : 1.0f;
    float4 b = sb[i];
    unsigned int o = order[i];
    float s = kScaler * kf;
    out[i * 6 + 0] = b.x * s;
    out[i * 6 + 1] = b.y * s;
    out[i * 6 + 2] = b.z * s;
    out[i * 6 + 3] = b.w * s;
    out[i * 6 + 4] = conf[2 * o] * kf;
    out[i * 6 + 5] = conf[2 * o + 1] * kf;
}

extern "C" void kernel_launch(void* const* d_in, const int* in_sizes, int n_in,
                              void* d_out, int out_size, void* d_ws, size_t ws_size,
                              hipStream_t stream) {
    const float* cls_conf = (const float*)d_in[0];   // (8192, 2)
    const float* bboxes   = (const float*)d_in[1];   // (8192, 4)
    float* out = (float*)d_out;                      // (8192, 6)

    char* ws = (char*)d_ws;
    unsigned long long* keys   = (unsigned long long*)(ws + 0);        //  64 KiB
    float4*             sb     = (float4*)(ws + 65536);                // 128 KiB
    unsigned int*       order  = (unsigned int*)(ws + 196608);         //  32 KiB
    unsigned long long* validw = (unsigned long long*)(ws + 229376);   //   1 KiB
    unsigned long long* mask   = (unsigned long long*)(ws + 237568);   //   8 MiB
    unsigned long long* keepw  = (unsigned long long*)(ws + 8626176);  //   1 KiB
    unsigned long long* diagG  = (unsigned long long*)(ws + 8627200);  //  64 KiB
    unsigned long long* dnzG   = (unsigned long long*)(ws + 8692736);  //   1 KiB
    unsigned long long* nzoffG = (unsigned long long*)(ws + 8693760);  //   1 KiB

    sort_local1<<<4, 1024, 0, stream>>>(cls_conf, keys);
    sort_global<<<16, 256, 0, stream>>>(keys, 4096, 2048);
    sort_local2<<<4, 1024, 0, stream>>>(keys, 4096, 0, bboxes, cls_conf, sb, order, validw, nzoffG);
    sort_global<<<16, 256, 0, stream>>>(keys, 8192, 4096);
    sort_global<<<16, 256, 0, stream>>>(keys, 8192, 2048);
    sort_local2<<<4, 1024, 0, stream>>>(keys, 8192, 1, bboxes, cls_conf, sb, order, validw, nzoffG);
    mask_kernel<<<dim3(32, 128), 256, 0, stream>>>(sb, validw, mask, diagG, dnzG, nzoffG);
    scan_kernel<<<1, 256, 0, stream>>>(mask, validw, diagG, dnzG, nzoffG, keepw);
    out_kernel<<<N_BOX / 256, 256, 0, stream>>>(sb, keepw, order, cls_conf, out);
}

// Round 5
// 274.030 us; speedup vs baseline: 1.2747x; 1.2747x over previous
//
#include <hip/hip_runtime.h>
#include <math.h>

#define N_BOX 8192
#define NW 128              // 8192 / 64 words per row
#define THR_C 0.7f
#define IOU_THR_C 0.5f
#define EPS_C 1e-9f

// SCALER = max(3508/1280, 2480/1280) computed in double then rounded to f32,
// matching numpy/jax float32 weak-typed scalar promotion.
__device__ __constant__ float kScaler = (float)(3508.0 / 1280.0);

// async global->LDS DMA, 16 B/lane: lane l's 16 B land at ldsbase + l*16.
static __device__ __forceinline__ void gload_lds16(const void* gp, void* lp) {
    __builtin_amdgcn_global_load_lds(
        (const __attribute__((address_space(1))) unsigned int*)gp,
        (__attribute__((address_space(3))) unsigned int*)lp,
        16, 0, 0);
}

// broadcast 64-bit value from (wave-uniform) source lane via v_readlane
static __device__ __forceinline__ unsigned long long bcast64(unsigned long long v, int sl) {
    unsigned int lo = __builtin_amdgcn_readlane((unsigned int)(v & 0xffffffffull), sl);
    unsigned int hi = __builtin_amdgcn_readlane((unsigned int)(v >> 32), sl);
    return ((unsigned long long)hi << 32) | lo;
}

static __device__ __forceinline__ unsigned long long make_key(const float* conf, int i) {
    float c0 = conf[2 * i], c1 = conf[2 * i + 1];
    bool valid = (c0 > THR_C) || (c1 > THR_C);
    float ms = valid ? fmaxf(c0, c1) : -INFINITY;
    unsigned int u = __float_as_uint(ms);
    unsigned int m = (u & 0x80000000u) ? ~u : (u | 0x80000000u); // ascending map
    unsigned int d = ~m;                                          // descending key
    return ((unsigned long long)d << 32) | (unsigned int)i;
}

// ---------------------------------------------------------------------------
// Sort: full 8192 bitonic network split so passes with j<=1024 run LDS-locally
// in 4 blocks of 2048 elements; only (k=4096,j=2048), (k=8192,j=4096),
// (k=8192,j=2048) are global passes. Directions use GLOBAL indices, so the
// network is bit-identical to the verified single-block version.
// ---------------------------------------------------------------------------
__global__ __launch_bounds__(1024) void sort_local1(const float* __restrict__ conf,
                                                    unsigned long long* __restrict__ keys) {
    __shared__ unsigned long long s[2048];
    int base = blockIdx.x * 2048;
    for (int l = threadIdx.x; l < 2048; l += 1024) s[l] = make_key(conf, base + l);
    __syncthreads();
    for (int k = 2; k <= 2048; k <<= 1) {
        for (int j = k >> 1; j > 0; j >>= 1) {
            int t = threadIdx.x;
            int i = ((t & ~(j - 1)) << 1) | (t & (j - 1));
            int p = i | j;
            bool up = (((base + i) & k) == 0);
            unsigned long long a = s[i], b = s[p];
            bool sw = up ? (a > b) : (a < b);
            if (sw) { s[i] = b; s[p] = a; }
            __syncthreads();
        }
    }
    for (int l = threadIdx.x; l < 2048; l += 1024) keys[base + l] = s[l];
}

__global__ void sort_global(unsigned long long* __restrict__ keys, int k, int j) {
    int t = blockIdx.x * 256 + threadIdx.x;          // 4096 threads
    int i = ((t & ~(j - 1)) << 1) | (t & (j - 1));
    int p = i | j;
    bool up = ((i & k) == 0);
    unsigned long long a = keys[i], b = keys[p];
    bool sw = up ? (a > b) : (a < b);
    if (sw) { keys[i] = b; keys[p] = a; }
}

// Local passes j=1024..1 for merge step k. When doGather!=0 (final k=8192 run)
// the sorted chunk is consumed directly from LDS: writes sb/order/validw and
// zero-inits nzoffG (block 0) instead of storing keys.
__global__ __launch_bounds__(1024) void sort_local2(unsigned long long* __restrict__ keys,
                                                    int k, int doGather,
                                                    const float* __restrict__ bboxes,
                                                    const float* __restrict__ conf,
                                                    float4* __restrict__ sb,
                                                    unsigned int* __restrict__ order,
                                                    unsigned long long* __restrict__ validw,
                                                    unsigned long long* __restrict__ nzoffG) {
    __shared__ unsigned long long s[2048];
    int base = blockIdx.x * 2048;
    for (int l = threadIdx.x; l < 2048; l += 1024) s[l] = keys[base + l];
    __syncthreads();
    for (int j = 1024; j > 0; j >>= 1) {
        int t = threadIdx.x;
        int i = ((t & ~(j - 1)) << 1) | (t & (j - 1));
        int p = i | j;
        bool up = (((base + i) & k) == 0);
        unsigned long long a = s[i], b = s[p];
        bool sw = up ? (a > b) : (a < b);
        if (sw) { s[i] = b; s[p] = a; }
        __syncthreads();
    }
    if (!doGather) {
        for (int l = threadIdx.x; l < 2048; l += 1024) keys[base + l] = s[l];
    } else {
        if (blockIdx.x == 0 && threadIdx.x < NW) nzoffG[threadIdx.x] = 0ull;
        for (int l = threadIdx.x; l < 2048; l += 1024) {
            int gi = base + l;
            unsigned int o = (unsigned int)(s[l] & 0xffffffffull);
            order[gi] = o;
            sb[gi] = ((const float4*)bboxes)[o];
            float c0 = conf[2 * o], c1 = conf[2 * o + 1];
            unsigned long long vb = __ballot((c0 > THR_C) || (c1 > THR_C));
            if ((l & 63) == 0) validw[gi >> 6] = vb;
        }
    }
}

// ---------------------------------------------------------------------------
// Kernel 3: suppression bit-matrix + sparsity metadata.
//   mask[i][w] bit b = (iou(i, 64w+b) > thr && 64w+b > i)
//   diagG[i]  = mask[i][i>>6]; dnzG[w] bit r = diag word nonzero;
//   nzoffG[w] bit r = row 64w+r has a nonzero off-diagonal word.
// Dead-work skip: invalid rows (never read downstream: nzoff/dnz exclude
// them, suppressing removed rows is idempotent) and lower-triangle words
// compute nothing; invalid rows also skip the mask store.
// ---------------------------------------------------------------------------
__global__ void mask_kernel(const float4* __restrict__ sb,
                            const unsigned long long* __restrict__ validw,
                            unsigned long long* __restrict__ mask,
                            unsigned long long* __restrict__ diagG,
                            unsigned long long* __restrict__ dnzG,
                            unsigned long long* __restrict__ nzoffG) {
    __shared__ float4 cb[64];
    __shared__ float carea[64];
    int w = blockIdx.y;
    if (threadIdx.x < 64) {
        float4 c = sb[(w << 6) + threadIdx.x];
        cb[threadIdx.x] = c;
        carea[threadIdx.x] = (c.z - c.x) * (c.w - c.y);
    }
    __syncthreads();
    int i = blockIdx.x * 256 + threadIdx.x;
    bool iv = (validw[i >> 6] >> (i & 63)) & 1ull;
    int jbase = w << 6;
    unsigned long long bits = 0ull;
    if (iv && (jbase + 63 > i)) {
        float4 r = sb[i];
        float ra = (r.z - r.x) * (r.w - r.y);
#pragma unroll 8
        for (int b = 0; b < 64; ++b) {
            float4 c = cb[b];
            float iw = fminf(r.z, c.z) - fmaxf(r.x, c.x);
            float ih = fminf(r.w, c.w) - fmaxf(r.y, c.y);
            iw = fmaxf(iw, 0.0f);
            ih = fmaxf(ih, 0.0f);
            float inter = iw * ih;
            float iou = inter / (ra + carea[b] - inter + EPS_C);
            if ((iou > IOU_THR_C) && ((jbase + b) > i)) bits |= (1ull << b);
        }
    }
    unsigned long long bb = __ballot(bits != 0ull);
    if ((i >> 6) == w) {
        diagG[i] = bits;
        if ((i & 63) == 0) dnzG[w] = bb;
    } else {
        if (bb && ((i & 63) == 0)) atomicOr(&nzoffG[i >> 6], bb);
    }
    if (iv) mask[(size_t)i * NW + w] = bits;
}

// ---------------------------------------------------------------------------
// Kernel 4: single-wave greedy scan — no barriers. Lane l owns removal words
// l and l+64 (registers). Per group g:
//   - broadcast rem word g via v_readlane (uniform index);
//   - ALL lanes redundantly run the in-group serial suppression over dnz rows
//     using LDS-resident diag words (preloaded once via global_load_lds) ->
//     kw = ~cur is uniform in-register, no further broadcast needed;
//   - apply: lane l loads mask[row][l] / mask[row][l+64] for kept&nzoff rows,
//     4 rows batched (8 independent coalesced loads per batch), OR into regs.
// ---------------------------------------------------------------------------
__global__ __launch_bounds__(64) void scan_kernel(const unsigned long long* __restrict__ mask,
                                                  const unsigned long long* __restrict__ validw,
                                                  const unsigned long long* __restrict__ diagG,
                                                  const unsigned long long* __restrict__ dnzG,
                                                  const unsigned long long* __restrict__ nzoffG,
                                                  unsigned long long* __restrict__ keepw) {
    __shared__ unsigned long long diagL[N_BOX];   // 64 KiB
    __shared__ unsigned long long dnzL[NW];
    __shared__ unsigned long long nzoffL[NW];
    __shared__ unsigned long long keepL[NW];
    int lane = threadIdx.x;
    // fire-and-forget DMA of all diag words into LDS (64 x 1 KiB chunks)
    for (int c = 0; c < 64; ++c)
        gload_lds16((const char*)diagG + (c << 10) + lane * 16,
                    (char*)diagL + (c << 10));
    dnzL[lane] = dnzG[lane];
    dnzL[lane + 64] = dnzG[lane + 64];
    nzoffL[lane] = nzoffG[lane];
    nzoffL[lane + 64] = nzoffG[lane + 64];
    unsigned long long r0 = ~validw[lane];        // removal words 0..63
    unsigned long long r1 = ~validw[lane + 64];   // removal words 64..127
    __builtin_amdgcn_s_waitcnt(0);                // drain DMA + loads
    for (int g = 0; g < NW; ++g) {
        unsigned long long dn = dnzL[g];          // LDS broadcast reads,
        unsigned long long nz = nzoffL[g];        // independent of rem chain
        unsigned long long cur = bcast64((g < 64) ? r0 : r1, g & 63);
        while (dn) {                              // in-group serial suppression
            int r = __builtin_ctzll(dn); dn &= dn - 1;
            if (!((cur >> r) & 1ull)) cur |= diagL[(g << 6) + r];
        }
        if (lane == 0) keepL[g] = cur;
        unsigned long long cw = ~cur & nz;        // kept rows w/ off-diag bits
        while (cw) {                              // 4-row batches, dup idempotent
            int a0 = __builtin_ctzll(cw); cw &= cw - 1;
            int a1 = a0, a2 = a0, a3 = a0;
            if (cw) { a1 = __builtin_ctzll(cw); cw &= cw - 1; }
            if (cw) { a2 = __builtin_ctzll(cw); cw &= cw - 1; }
            if (cw) { a3 = __builtin_ctzll(cw); cw &= cw - 1; }
            const unsigned long long* m0 = mask + (size_t)((g << 6) + a0) * NW;
            const unsigned long long* m1 = mask + (size_t)((g << 6) + a1) * NW;
            const unsigned long long* m2 = mask + (size_t)((g << 6) + a2) * NW;
            const unsigned long long* m3 = mask + (size_t)((g << 6) + a3) * NW;
            r0 |= m0[lane] | m1[lane] | m2[lane] | m3[lane];
            r1 |= m0[lane + 64] | m1[lane + 64] | m2[lane + 64] | m3[lane + 64];
        }
    }
    keepw[lane] = keepL[lane];
    keepw[lane + 64] = keepL[lane + 64];
}

// ---------------------------------------------------------------------------
// Kernel 5: write (N,6) output: [boxes*SCALER*kf, conf*kf]
// ---------------------------------------------------------------------------
__global__ void out_kernel(const float4* __restrict__ sb,
                           const unsigned long long* __restrict__ keepw,
                           const unsigned int* __restrict__ order,
                           const float* __restrict__ conf,
                           float* __restrict__ out) {
    int i = blockIdx.x * 256 + threadIdx.x;
    float kf = ((keepw[i >> 6] >> (i & 63)) & 1ull) ? 0.0f : 1.0f;
    float4 b = sb[i];
    unsigned int o = order[i];
    float s = kScaler * kf;
    out[i * 6 + 0] = b.x * s;
    out[i * 6 + 1] = b.y * s;
    out[i * 6 + 2] = b.z * s;
    out[i * 6 + 3] = b.w * s;
    out[i * 6 + 4] = conf[2 * o] * kf;
    out[i * 6 + 5] = conf[2 * o + 1] * kf;
}

extern "C" void kernel_launch(void* const* d_in, const int* in_sizes, int n_in,
                              void* d_out, int out_size, void* d_ws, size_t ws_size,
                              hipStream_t stream) {
    const float* cls_conf = (const float*)d_in[0];   // (8192, 2)
    const float* bboxes   = (const float*)d_in[1];   // (8192, 4)
    float* out = (float*)d_out;                      // (8192, 6)

    char* ws = (char*)d_ws;
    unsigned long long* keys   = (unsigned long long*)(ws + 0);        //  64 KiB
    float4*             sb     = (float4*)(ws + 65536);                // 128 KiB
    unsigned int*       order  = (unsigned int*)(ws + 196608);         //  32 KiB
    unsigned long long* validw = (unsigned long long*)(ws + 229376);   //   1 KiB
    unsigned long long* mask   = (unsigned long long*)(ws + 237568);   //   8 MiB
    unsigned long long* keepw  = (unsigned long long*)(ws + 8626176);  //   1 KiB
    unsigned long long* diagG  = (unsigned long long*)(ws + 8627200);  //  64 KiB
    unsigned long long* dnzG   = (unsigned long long*)(ws + 8692736);  //   1 KiB
    unsigned long long* nzoffG = (unsigned long long*)(ws + 8693760);  //   1 KiB

    sort_local1<<<4, 1024, 0, stream>>>(cls_conf, keys);
    sort_global<<<16, 256, 0, stream>>>(keys, 4096, 2048);
    sort_local2<<<4, 1024, 0, stream>>>(keys, 4096, 0, bboxes, cls_conf, sb, order, validw, nzoffG);
    sort_global<<<16, 256, 0, stream>>>(keys, 8192, 4096);
    sort_global<<<16, 256, 0, stream>>>(keys, 8192, 2048);
    sort_local2<<<4, 1024, 0, stream>>>(keys, 8192, 1, bboxes, cls_conf, sb, order, validw, nzoffG);
    mask_kernel<<<dim3(32, 128), 256, 0, stream>>>(sb, validw, mask, diagG, dnzG, nzoffG);
    scan_kernel<<<1, 64, 0, stream>>>(mask, validw, diagG, dnzG, nzoffG, keepw);
    out_kernel<<<N_BOX / 256, 256, 0, stream>>>(sb, keepw, order, cls_conf, out);
}